// Round 13
// baseline (1319.169 us; speedup 1.0000x reference)
//
#include <hip/hip_runtime.h>
#include <math.h>

// ---- problem constants ----
#define BATCH   16
#define SEQ     4096
#define DMODEL  64
#define DINNER  128
#define DSTATE  32
#define NHEADS  2
#define HEADDIM 64
#define CONVDIM 192            // DINNER + 2*DSTATE
#define PROJ    322            // 2*DINNER + 2*DSTATE + NHEADS
#define QC      64             // chunk length for SSD scan
#define NCHUNK  (SEQ/QC)       // 64
#define BL      (BATCH*SEQ)    // 65536 rows
#define NPAD    336            // PROJ padded to 21*16 for MFMA col tiles

typedef __attribute__((ext_vector_type(8))) short short8;   // 8 bf16 (4 VGPRs)
typedef __attribute__((ext_vector_type(4))) float f32x4;    // MFMA C/D

__device__ inline unsigned short f2b(float f){
  union { float f; unsigned u; } v; v.f = f;
  unsigned r = v.u + 0x7FFF + ((v.u >> 16) & 1);   // round-to-nearest-even
  return (unsigned short)(r >> 16);
}
__device__ inline float b2f(unsigned short s){
  union { unsigned u; float f; } v; v.u = ((unsigned)s) << 16; return v.f;
}
// hi/lo split: x ~= hi + lo, residual ~2^-18 * x
__device__ inline void split2(float x, unsigned short& h, unsigned short& l){
  unsigned short hh = f2b(x);
  h = hh;
  l = f2b(x - b2f(hh));
}

// ---- static device scratch ----
// fp32 on the cross-kernel signal path (R5/R6 post-mortem: bf16 there fails).
__device__ float g_z   [(size_t)BL*DINNER];    // z (dense fp32)
__device__ float g_xbc [(size_t)BL*CONVDIM];   // pre-conv xBC (dense fp32)
__device__ float g_y   [(size_t)BL*DINNER];    // y_intra + D*x (fp32, exact fold)
__device__ unsigned short g_C[(size_t)BL*DSTATE]; // post-conv C (bf16, chunkA-class)
__device__ float g_dt  [BATCH*NHEADS*SEQ];
__device__ float g_cum [BATCH*NHEADS*SEQ];
__device__ float g_ctot[BATCH*NHEADS*NCHUNK];
__device__ float g_S   [BATCH*NHEADS*NCHUNK*DSTATE*HEADDIM];
__device__ float g_H   [BATCH*NHEADS*NCHUNK*DSTATE*HEADDIM];
__device__ float g_ping0[(size_t)BL*DMODEL];
__device__ float g_ping1[(size_t)BL*DMODEL];
__device__ unsigned short g_WinTh [8*NPAD*DMODEL];
__device__ unsigned short g_WinTl [8*NPAD*DMODEL];
__device__ unsigned short g_WoutTh[8*DMODEL*DINNER];
__device__ unsigned short g_WoutTl[8*DMODEL*DINNER];

// ---- K0: prep transposed hi/lo bf16 weights ----
__global__ __launch_bounds__(256) void k_prep(const float* __restrict__ Win,
                                              const float* __restrict__ Wout,
                                              const float* __restrict__ normw) {
  const int idx = blockIdx.x*256 + threadIdx.x;
  const int NW = 8*NPAD*DMODEL;
  if (idx < NW) {
    int layer = idx / (NPAD*DMODEL);
    int rem   = idx - layer*(NPAD*DMODEL);
    int n = rem >> 6, k = rem & 63;
    float v = (n < PROJ) ? Win[(size_t)layer*DMODEL*PROJ + k*PROJ + n] : 0.f;
    split2(v, g_WinTh[idx], g_WinTl[idx]);
  } else {
    int i2 = idx - NW;
    if (i2 < 8*DMODEL*DINNER) {
      int layer = i2 / (DMODEL*DINNER);
      int rem   = i2 - layer*(DMODEL*DINNER);
      int n = rem >> 7, k = rem & 127;
      float v = Wout[(size_t)layer*DINNER*DMODEL + k*DMODEL + n] * normw[layer*DINNER + k];
      split2(v, g_WoutTh[i2], g_WoutTl[i2]);
    }
  }
}

// ---- K1 (MFMA, split-precision): in_proj -> g_z | g_xbc ; fused fp32 dt+cumsum ----
// Column-split grid: blockIdx.y=0 -> groups 0..1 (z) + dt path; y=1 -> groups 2..4 (xbc).
__global__ __launch_bounds__(256) void k_inproj(const float* __restrict__ xext, int sel,
                                                const unsigned short* __restrict__ WinTh,
                                                const unsigned short* __restrict__ WinTl,
                                                const float* __restrict__ Win,
                                                const float* __restrict__ dt_bias,
                                                const float* __restrict__ A_log) {
  __shared__ unsigned short Xhl[2][64][72];   // [0]=hi, [1]=lo; reused as store staging
  const float* __restrict__ X = (sel==0) ? xext : (sel==1 ? g_ping0 : g_ping1);
  const int bx = blockIdx.x;
  const int part = blockIdx.y;                // 0: z+dt, 1: xbc
  const int row0 = bx * 64;
  const int tid = threadIdx.x;
#pragma unroll
  for (int j=0;j<4;j++){
    int e = tid + j*256; int r = e>>4, c4 = (e&15)*4;
    float4 v = *(const float4*)&X[(size_t)(row0+r)*DMODEL + c4];
    split2(v.x, Xhl[0][r][c4+0], Xhl[1][r][c4+0]);
    split2(v.y, Xhl[0][r][c4+1], Xhl[1][r][c4+1]);
    split2(v.z, Xhl[0][r][c4+2], Xhl[1][r][c4+2]);
    split2(v.w, Xhl[0][r][c4+3], Xhl[1][r][c4+3]);
  }
  const int w = tid>>6, l = tid&63, lane15 = l&15, quad = l>>4;
  if (part == 0 && w < 2) {   // fp32 dt path (only in the z-partition)
    const int h = w, t = l;
    float acc = 0.f;
    const float* xr = &X[(size_t)(row0+t)*DMODEL];
#pragma unroll
    for (int k=0;k<64;k++) acc = fmaf(xr[k], Win[k*PROJ + (DINNER+CONVDIM) + h], acc);
    float xv = acc + dt_bias[h];
    float dtv = (xv > 20.f) ? xv : log1pf(expf(xv));
    float A = -expf(A_log[h]);
    float cum = dtv * A;
#pragma unroll
    for (int off=1; off<64; off<<=1){
      float v = __shfl_up(cum, off);
      if (t >= off) cum += v;
    }
    const int b = bx>>6, ch = bx&63;
    const int base = (b*NHEADS + h)*SEQ + ch*QC + t;
    g_dt [base] = dtv;
    g_cum[base] = cum;
    if (t == 63) g_ctot[(b*NHEADS+h)*NCHUNK + ch] = cum;
  }
  __syncthreads();
  short8 a0h = *(const short8*)&Xhl[0][16*w + lane15][quad*8];
  short8 a1h = *(const short8*)&Xhl[0][16*w + lane15][quad*8 + 32];
  short8 a0l = *(const short8*)&Xhl[1][16*w + lane15][quad*8];
  short8 a1l = *(const short8*)&Xhl[1][16*w + lane15][quad*8 + 32];
  __syncthreads();   // all fragments in regs; Xhl now free for staging
  float (*stg)[68] = (float(*)[68])((float*)&Xhl[0][0][0] + (size_t)w*16*68);  // per-wave 16x68
  const int gBeg = part ? 2 : 0;
  const int gEnd = part ? 5 : 2;
#pragma unroll 1
  for (int g5=gBeg; g5<gEnd; g5++){         // groups of 4 col-tiles; 0..1=z, 2..4=xbc
    f32x4 acc4[4];
#pragma unroll
    for (int tt=0; tt<4; tt++){
      int t = g5*4 + tt;
      const unsigned short* bph = &WinTh[(16*t + lane15)*64 + quad*8];
      const unsigned short* bpl = &WinTl[(16*t + lane15)*64 + quad*8];
      short8 b0h = *(const short8*)bph;
      short8 b1h = *(const short8*)(bph + 32);
      short8 b0l = *(const short8*)bpl;
      short8 b1l = *(const short8*)(bpl + 32);
      f32x4 acc = {0.f,0.f,0.f,0.f};
      acc = __builtin_amdgcn_mfma_f32_16x16x32_bf16(a0h, b0h, acc, 0, 0, 0);
      acc = __builtin_amdgcn_mfma_f32_16x16x32_bf16(a1h, b1h, acc, 0, 0, 0);
      acc = __builtin_amdgcn_mfma_f32_16x16x32_bf16(a0l, b0h, acc, 0, 0, 0);
      acc = __builtin_amdgcn_mfma_f32_16x16x32_bf16(a1l, b1h, acc, 0, 0, 0);
      acc = __builtin_amdgcn_mfma_f32_16x16x32_bf16(a0h, b0l, acc, 0, 0, 0);
      acc = __builtin_amdgcn_mfma_f32_16x16x32_bf16(a1h, b1l, acc, 0, 0, 0);
      acc4[tt] = acc;
    }
    // stage to per-wave LDS tile (wave-private, no barrier needed)
#pragma unroll
    for (int tt=0; tt<4; tt++)
#pragma unroll
      for (int r=0;r<4;r++)
        stg[quad*4+r][tt*16+lane15] = acc4[tt][r];
    // drain: 4 dwordx4 per lane, 1KB contiguous per 16 lanes
#pragma unroll
    for (int it=0; it<4; it++){
      int e = it*64 + l;
      int lr = e>>4, c4 = (e&15)<<2;
      float4 v = *(const float4*)&stg[lr][c4];
      size_t grow = row0 + 16*w + lr;
      int gcol = g5*64 + c4;
      if (g5 < 2) *(float4*)&g_z  [grow*DINNER  + gcol]          = v;
      else        *(float4*)&g_xbc[grow*CONVDIM + gcol - DINNER] = v;
    }
  }
}

// ---- K4 (MFMA): per-(b,h,chunk): register-window conv+silu, then G, Y(+exact D*x), S ----
__global__ __launch_bounds__(256,3) void k_chunkA(const float* __restrict__ conv_w,
                                                  const float* __restrict__ conv_b,
                                                  const float* __restrict__ Dp) {
  __shared__ float Xf[64][66];             // fp32 post-conv x (transposed), 16.9 KB
  __shared__ unsigned short Xt [64][72];   // X^T (bf16)
  __shared__ unsigned short Gsh[64][72];   // masked G[t][s]
  __shared__ unsigned short Bt [32][72];   // (ew*B)^T
  __shared__ unsigned short Bsh[64][40];   // B[s][n]
  __shared__ unsigned short Csh[64][40];   // C[t][n]
  __shared__ float cuml[QC], dtl[QC], ewl[QC];
  const int bx = blockIdx.x; const int b = bx>>7, h=(bx>>6)&1, ch=bx&63;
  const int tid = threadIdx.x;
  const size_t row0 = (size_t)b*SEQ + (size_t)ch*QC;
  const int cbase = (b*NHEADS+h)*SEQ + ch*QC;
  const float dph = Dp[h];
  if (tid < QC){
    float cl = g_cum[cbase+63];
    float cu = g_cum[cbase+tid], dtv = g_dt[cbase+tid];
    cuml[tid] = cu; dtl[tid] = dtv;
    ewl[tid] = expf(cl - cu) * dtv;
  }
  const int cc = tid & 127, half = tid >> 7, t0 = half*32;
  const int gch = (cc < 64) ? (h*64 + cc) : (64 + cc);
  const float w0 = conv_w[gch*4+0], w1 = conv_w[gch*4+1], w2 = conv_w[gch*4+2], w3 = conv_w[gch*4+3];
  const float bb = conv_b[gch];
  float v0, v1, v2;
  if (ch==0 && half==0){ v0=0.f; v1=0.f; v2=0.f; }
  else {
    v0 = g_xbc[(row0+t0-3)*CONVDIM + gch];
    v1 = g_xbc[(row0+t0-2)*CONVDIM + gch];
    v2 = g_xbc[(row0+t0-1)*CONVDIM + gch];
  }
  __syncthreads();   // cuml/dtl/ewl visible
  if (cc < 64){
#pragma unroll
    for (int blk=0; blk<4; ++blk){
      unsigned short xb[8];
#pragma unroll
      for (int j=0;j<8;j++){
        int t = t0 + blk*8 + j;
        float v3 = g_xbc[(row0+t)*CONVDIM + gch];
        float a = fmaf(w0,v0, fmaf(w1,v1, fmaf(w2,v2, fmaf(w3,v3, bb))));
        float sv = a / (1.f + expf(-a));
        Xf[cc][t] = sv;
        xb[j] = f2b(sv);
        v0=v1; v1=v2; v2=v3;
      }
      *(short8*)&Xt[cc][t0 + blk*8] = *(const short8*)xb;
    }
  } else if (cc < 96){
    const int n = cc - 64;
#pragma unroll
    for (int blk=0; blk<4; ++blk){
      unsigned short bt8[8];
#pragma unroll
      for (int j=0;j<8;j++){
        int t = t0 + blk*8 + j;
        float v3 = g_xbc[(row0+t)*CONVDIM + gch];
        float a = fmaf(w0,v0, fmaf(w1,v1, fmaf(w2,v2, fmaf(w3,v3, bb))));
        float sv = a / (1.f + expf(-a));
        Bsh[t][n] = f2b(sv);
        bt8[j] = f2b(sv * ewl[t]);
        v0=v1; v1=v2; v2=v3;
      }
      *(short8*)&Bt[n][t0 + blk*8] = *(const short8*)bt8;
    }
  } else {
    const int n = cc - 96;
#pragma unroll 4
    for (int t=t0; t<t0+32; t++){
      float v3 = g_xbc[(row0+t)*CONVDIM + gch];
      float a = fmaf(w0,v0, fmaf(w1,v1, fmaf(w2,v2, fmaf(w3,v3, bb))));
      float sv = a / (1.f + expf(-a));
      Csh[t][n] = f2b(sv);
      if (h == 0) g_C[(row0+t)*DSTATE + n] = f2b(sv);
      v0=v1; v1=v2; v2=v3;
    }
  }
  __syncthreads();
  const int w = tid>>6, l = tid&63, lane15 = l&15, quad = l>>4;
  short8 afr = *(const short8*)&Csh[16*w + lane15][quad*8];
  f32x4 gacc[4];
#pragma unroll
  for (int tn=0;tn<4;tn++){
    short8 bfr = *(const short8*)&Bsh[16*tn + lane15][quad*8];
    f32x4 z = {0.f,0.f,0.f,0.f};
    gacc[tn] = __builtin_amdgcn_mfma_f32_16x16x32_bf16(afr, bfr, z, 0, 0, 0);
  }
#pragma unroll
  for (int tn=0;tn<4;tn++){
    int s = 16*tn + lane15;
    float cs = cuml[s], ds = dtl[s];
#pragma unroll
    for (int r=0;r<4;r++){
      int t = 16*w + quad*4 + r;
      float gv = 0.f;
      if (s <= t) gv = expf(cuml[t]-cs) * ds * gacc[tn][r];
      Gsh[t][s] = f2b(gv);
    }
  }
  __syncthreads();
#pragma unroll
  for (int tn=0;tn<4;tn++){
    f32x4 acc = {0.f,0.f,0.f,0.f};
#pragma unroll
    for (int ks=0;ks<2;ks++){
      short8 a  = *(const short8*)&Gsh[16*w  + lane15][quad*8 + 32*ks];
      short8 bf = *(const short8*)&Xt [16*tn + lane15][quad*8 + 32*ks];
      acc = __builtin_amdgcn_mfma_f32_16x16x32_bf16(a, bf, acc, 0, 0, 0);
    }
    int p = 16*tn + lane15;
#pragma unroll
    for (int r=0;r<4;r++){
      int t = 16*w + quad*4 + r;
      g_y[(row0+t)*DINNER + h*HEADDIM + p] = acc[r] + dph * Xf[p][t];  // exact fp32 fold
    }
  }
  const size_t sb = (size_t)((b*NHEADS+h)*NCHUNK + ch) * (DSTATE*HEADDIM);
  const int tm2 = w & 1, tnb = (w>>1)*2;
#pragma unroll
  for (int tt=0;tt<2;tt++){
    int tn2 = tnb + tt;
    f32x4 acc = {0.f,0.f,0.f,0.f};
#pragma unroll
    for (int ks=0;ks<2;ks++){
      short8 a  = *(const short8*)&Bt[16*tm2 + lane15][quad*8 + 32*ks];
      short8 bf = *(const short8*)&Xt[16*tn2 + lane15][quad*8 + 32*ks];
      acc = __builtin_amdgcn_mfma_f32_16x16x32_bf16(a, bf, acc, 0, 0, 0);
    }
    int p = 16*tn2 + lane15;
#pragma unroll
    for (int r=0;r<4;r++){
      int n = 16*tm2 + quad*4 + r;
      g_S[sb + n*HEADDIM + p] = acc[r];
    }
  }
}

// ---- K5: sequential-over-chunks state scan (software-pipelined, bit-identical chain) ----
__global__ __launch_bounds__(256) void k_chunkScan() {
  __shared__ float dAc[NCHUNK];            // exp(ctot) per chunk (uniform per block)
  const int idx = blockIdx.x*256 + threadIdx.x;
  const int np = idx & 2047;
  const int bh = idx >> 11;                // uniform within a 256-thread block
  if (threadIdx.x < NCHUNK) dAc[threadIdx.x] = expf(g_ctot[bh*NCHUNK + threadIdx.x]);
  __syncthreads();
  float h = 0.f;
  const size_t base = (size_t)bh*NCHUNK*2048 + np;
#pragma unroll 1
  for (int k0=0; k0<NCHUNK; k0+=8){
    float s[8];
#pragma unroll
    for (int j=0;j<8;j++) s[j] = g_S[base + (size_t)(k0+j)*2048];   // 8 independent loads
    float hs[8];
#pragma unroll
    for (int j=0;j<8;j++){
      hs[j] = h;                                                     // state at chunk start
      h = h*dAc[k0+j] + s[j];                                        // same chain order
    }
#pragma unroll
    for (int j=0;j<8;j++) g_H[base + (size_t)(k0+j)*2048] = hs[j];
  }
}

// ---- K6 (fused): inter-chunk y + gate + RMSNorm + split-MFMA out_proj ----
// Epilogue: per-wave LDS transpose (reusing yAh) -> 4KB contiguous row stores.
__global__ __launch_bounds__(256,3) void k_fusedC(const unsigned short* __restrict__ WoutTh,
                                                  const unsigned short* __restrict__ WoutTl,
                                                  float* __restrict__ dout, int dsel) {
  __shared__ float Cl[QC][DSTATE+1];             // 8.4 KB
  __shared__ float ec[NHEADS][QC];
  __shared__ unsigned short yAh[64][136];        // 17.4 KB (reused as store staging)
  __shared__ unsigned short yAl[64][136];        // 17.4 KB
  float* __restrict__ out = (dsel==0) ? g_ping0 : (dsel==1 ? g_ping1 : dout);
  const int bx = blockIdx.x; const int b = bx>>6, ch = bx&63;
  const int tid = threadIdx.x;
  const size_t row0 = (size_t)b*SEQ + (size_t)ch*QC;
  const int w = tid>>6, l = tid&63, lane15 = l&15, quad = l>>4;
#pragma unroll
  for (int j=0;j<8;j++){ int e=tid+j*256; int s=e>>5, n=e&31;
    Cl[s][n] = b2f(g_C[(row0+s)*DSTATE + n]); }
  if (tid < 128){ int h_=tid>>6, s=tid&63;
    ec[h_][s] = expf(g_cum[(b*NHEADS+h_)*SEQ + ch*QC + s]); }
  float hr[64];
  {
    const float* H0 = &g_H[(size_t)((b*NHEADS+0)*NCHUNK + ch)*2048];
    const float* H1 = &g_H[(size_t)((b*NHEADS+1)*NCHUNK + ch)*2048];
#pragma unroll
    for (int n=0;n<32;n++){ hr[n] = H0[n*64 + l]; hr[32+n] = H1[n*64 + l]; }
  }
  __syncthreads();
#pragma unroll 1
  for (int i=0;i<16;i++){
    const int r = 16*w + i;
    const size_t row = row0 + r;
    float d0 = 0.f, d1 = 0.f;
#pragma unroll
    for (int n=0;n<32;n++){
      float c = Cl[r][n];
      d0 = fmaf(c, hr[n],    d0);
      d1 = fmaf(c, hr[32+n], d1);
    }
    float yv0 = g_y[row*DINNER + l]      + ec[0][r]*d0;
    float yv1 = g_y[row*DINNER + l + 64] + ec[1][r]*d1;
    float z0 = g_z[row*DINNER + l];
    float z1 = g_z[row*DINNER + l + 64];
    yv0 *= z0 / (1.f + expf(-z0));
    yv1 *= z1 / (1.f + expf(-z1));
    float ss = yv0*yv0 + yv1*yv1;
#pragma unroll
    for (int off=32; off>=1; off>>=1) ss += __shfl_xor(ss, off);
    float sc = rsqrtf(ss*(1.f/128.f) + 1e-5f);
    split2(yv0*sc, yAh[r][l],    yAl[r][l]);
    split2(yv1*sc, yAh[r][l+64], yAl[r][l+64]);
  }
  __syncthreads();
  short8 afh[4], afl[4];
#pragma unroll
  for (int ks=0;ks<4;ks++){
    afh[ks] = *(const short8*)&yAh[16*w + lane15][quad*8 + 32*ks];
    afl[ks] = *(const short8*)&yAl[16*w + lane15][quad*8 + 32*ks];
  }
  __syncthreads();   // all yAh reads done; reuse as per-wave staging
  float (*stgF)[68] = (float(*)[68])((float*)&yAh[0][0] + (size_t)w*16*68);
#pragma unroll
  for (int tc=0;tc<4;tc++){
    f32x4 acc = {0.f,0.f,0.f,0.f};
#pragma unroll
    for (int ks=0;ks<4;ks++){
      const unsigned short* bph = &WoutTh[(16*tc + lane15)*DINNER + quad*8 + 32*ks];
      const unsigned short* bpl = &WoutTl[(16*tc + lane15)*DINNER + quad*8 + 32*ks];
      short8 bh  = *(const short8*)bph;
      short8 blo = *(const short8*)bpl;
      acc = __builtin_amdgcn_mfma_f32_16x16x32_bf16(afh[ks], bh,  acc, 0, 0, 0);
      acc = __builtin_amdgcn_mfma_f32_16x16x32_bf16(afl[ks], bh,  acc, 0, 0, 0);
      acc = __builtin_amdgcn_mfma_f32_16x16x32_bf16(afh[ks], blo, acc, 0, 0, 0);
    }
#pragma unroll
    for (int r=0;r<4;r++)
      stgF[quad*4+r][tc*16+lane15] = acc[r];
  }
  // wave-private drain: 16 rows x 256B = 4KB contiguous per wave
#pragma unroll
  for (int it=0; it<4; it++){
    int e = it*64 + l;
    int lr = e>>4, c4 = (e&15)<<2;
    float4 v = *(const float4*)&stgF[lr][c4];
    *(float4*)&out[(row0 + 16*w + lr)*DMODEL + c4] = v;
  }
}

extern "C" void kernel_launch(void* const* d_in, const int* in_sizes, int n_in,
                              void* d_out, int out_size, void* d_ws, size_t ws_size,
                              hipStream_t stream) {
  (void)in_sizes; (void)n_in; (void)d_ws; (void)ws_size; (void)out_size;
  const float* x       = (const float*)d_in[0];
  const float* Win     = (const float*)d_in[1];
  const float* conv_w  = (const float*)d_in[2];
  const float* conv_b  = (const float*)d_in[3];
  const float* dt_bias = (const float*)d_in[4];
  const float* A_log   = (const float*)d_in[5];
  const float* Dp      = (const float*)d_in[6];
  const float* norm_w  = (const float*)d_in[7];
  const float* Wout    = (const float*)d_in[8];

  k_prep<<<(8*(NPAD*DMODEL + DMODEL*DINNER) + 255)/256, 256, 0, stream>>>(Win, Wout, norm_w);

  unsigned short *winTh, *winTl, *woutTh, *woutTl;
  hipGetSymbolAddress((void**)&winTh,  HIP_SYMBOL(g_WinTh));
  hipGetSymbolAddress((void**)&winTl,  HIP_SYMBOL(g_WinTl));
  hipGetSymbolAddress((void**)&woutTh, HIP_SYMBOL(g_WoutTh));
  hipGetSymbolAddress((void**)&woutTl, HIP_SYMBOL(g_WoutTl));

  for (int layer = 0; layer < 8; ++layer) {
    const int insel = (layer==0) ? 0 : ((((layer-1)&1)==0) ? 1 : 2);
    const int dsel  = (layer==7) ? 2 : ((layer&1)==0 ? 0 : 1);

    k_inproj<<<dim3(BL/64, 2), 256, 0, stream>>>(x, insel,
                                        winTh + (size_t)layer*NPAD*DMODEL,
                                        winTl + (size_t)layer*NPAD*DMODEL,
                                        Win + (size_t)layer*DMODEL*PROJ,
                                        dt_bias + layer*NHEADS, A_log + layer*NHEADS);
    k_chunkA<<<BATCH*NHEADS*NCHUNK, 256, 0, stream>>>(conv_w + (size_t)layer*CONVDIM*4,
                                                      conv_b + (size_t)layer*CONVDIM,
                                                      Dp + layer*NHEADS);
    k_chunkScan<<<(BATCH*NHEADS*DSTATE*HEADDIM)/256, 256, 0, stream>>>();
    k_fusedC<<<BATCH*NCHUNK, 256, 0, stream>>>(woutTh + (size_t)layer*DMODEL*DINNER,
                                               woutTl + (size_t)layer*DMODEL*DINNER,
                                               (float*)d_out, dsel);
  }
}

// Round 14
// 1240.570 us; speedup vs baseline: 1.0634x; 1.0634x over previous
//
#include <hip/hip_runtime.h>
#include <math.h>

// ---- problem constants ----
#define BATCH   16
#define SEQ     4096
#define DMODEL  64
#define DINNER  128
#define DSTATE  32
#define NHEADS  2
#define HEADDIM 64
#define CONVDIM 192            // DINNER + 2*DSTATE
#define PROJ    322            // 2*DINNER + 2*DSTATE + NHEADS
#define QC      64             // chunk length for SSD scan
#define NCHUNK  (SEQ/QC)       // 64
#define BL      (BATCH*SEQ)    // 65536 rows
#define NPAD    336            // PROJ padded to 21*16 for MFMA col tiles

typedef __attribute__((ext_vector_type(8))) short short8;   // 8 bf16 (4 VGPRs)
typedef __attribute__((ext_vector_type(4))) float f32x4;    // MFMA C/D

__device__ inline unsigned short f2b(float f){
  union { float f; unsigned u; } v; v.f = f;
  unsigned r = v.u + 0x7FFF + ((v.u >> 16) & 1);   // round-to-nearest-even
  return (unsigned short)(r >> 16);
}
__device__ inline float b2f(unsigned short s){
  union { unsigned u; float f; } v; v.u = ((unsigned)s) << 16; return v.f;
}
// hi/lo split: x ~= hi + lo, residual ~2^-18 * x
__device__ inline void split2(float x, unsigned short& h, unsigned short& l){
  unsigned short hh = f2b(x);
  h = hh;
  l = f2b(x - b2f(hh));
}

// ---- static device scratch ----
// fp32 on the cross-kernel signal path (R5/R6 post-mortem: bf16 there fails).
__device__ float g_z   [(size_t)BL*DINNER];    // z (dense fp32)
__device__ float g_xbc [(size_t)BL*CONVDIM];   // pre-conv xBC (dense fp32)
__device__ float g_y   [(size_t)BL*DINNER];    // y_intra + D*x (fp32, exact fold)
__device__ unsigned short g_C[(size_t)BL*DSTATE]; // post-conv C (bf16, chunkA-class)
__device__ float g_dt  [BATCH*NHEADS*SEQ];
__device__ float g_cum [BATCH*NHEADS*SEQ];
__device__ float g_ctot[BATCH*NHEADS*NCHUNK];
__device__ float g_S   [BATCH*NHEADS*NCHUNK*DSTATE*HEADDIM];
__device__ float g_H   [BATCH*NHEADS*NCHUNK*DSTATE*HEADDIM];
__device__ float g_ping0[(size_t)BL*DMODEL];
__device__ float g_ping1[(size_t)BL*DMODEL];
__device__ unsigned short g_WinTh [8*NPAD*DMODEL];
__device__ unsigned short g_WinTl [8*NPAD*DMODEL];
__device__ unsigned short g_WoutTh[8*DMODEL*DINNER];
__device__ unsigned short g_WoutTl[8*DMODEL*DINNER];

// ---- K0: prep transposed hi/lo bf16 weights ----
__global__ __launch_bounds__(256) void k_prep(const float* __restrict__ Win,
                                              const float* __restrict__ Wout,
                                              const float* __restrict__ normw) {
  const int idx = blockIdx.x*256 + threadIdx.x;
  const int NW = 8*NPAD*DMODEL;
  if (idx < NW) {
    int layer = idx / (NPAD*DMODEL);
    int rem   = idx - layer*(NPAD*DMODEL);
    int n = rem >> 6, k = rem & 63;
    float v = (n < PROJ) ? Win[(size_t)layer*DMODEL*PROJ + k*PROJ + n] : 0.f;
    split2(v, g_WinTh[idx], g_WinTl[idx]);
  } else {
    int i2 = idx - NW;
    if (i2 < 8*DMODEL*DINNER) {
      int layer = i2 / (DMODEL*DINNER);
      int rem   = i2 - layer*(DMODEL*DINNER);
      int n = rem >> 7, k = rem & 127;
      float v = Wout[(size_t)layer*DINNER*DMODEL + k*DMODEL + n] * normw[layer*DINNER + k];
      split2(v, g_WoutTh[i2], g_WoutTl[i2]);
    }
  }
}

// ---- K1 (MFMA, split-precision): in_proj -> g_z | g_xbc ; fused fp32 dt+cumsum ----
// (R12 version: single partition, per-wave LDS-transpose store epilogue.)
__global__ __launch_bounds__(256) void k_inproj(const float* __restrict__ xext, int sel,
                                                const unsigned short* __restrict__ WinTh,
                                                const unsigned short* __restrict__ WinTl,
                                                const float* __restrict__ Win,
                                                const float* __restrict__ dt_bias,
                                                const float* __restrict__ A_log) {
  __shared__ unsigned short Xhl[2][64][72];   // [0]=hi, [1]=lo; reused as store staging
  const float* __restrict__ X = (sel==0) ? xext : (sel==1 ? g_ping0 : g_ping1);
  const int bx = blockIdx.x;
  const int row0 = bx * 64;
  const int tid = threadIdx.x;
#pragma unroll
  for (int j=0;j<4;j++){
    int e = tid + j*256; int r = e>>4, c4 = (e&15)*4;
    float4 v = *(const float4*)&X[(size_t)(row0+r)*DMODEL + c4];
    split2(v.x, Xhl[0][r][c4+0], Xhl[1][r][c4+0]);
    split2(v.y, Xhl[0][r][c4+1], Xhl[1][r][c4+1]);
    split2(v.z, Xhl[0][r][c4+2], Xhl[1][r][c4+2]);
    split2(v.w, Xhl[0][r][c4+3], Xhl[1][r][c4+3]);
  }
  const int w = tid>>6, l = tid&63, lane15 = l&15, quad = l>>4;
  if (w < 2) {   // fp32 dt path
    const int h = w, t = l;
    float acc = 0.f;
    const float* xr = &X[(size_t)(row0+t)*DMODEL];
#pragma unroll
    for (int k=0;k<64;k++) acc = fmaf(xr[k], Win[k*PROJ + (DINNER+CONVDIM) + h], acc);
    float xv = acc + dt_bias[h];
    float dtv = (xv > 20.f) ? xv : log1pf(expf(xv));
    float A = -expf(A_log[h]);
    float cum = dtv * A;
#pragma unroll
    for (int off=1; off<64; off<<=1){
      float v = __shfl_up(cum, off);
      if (t >= off) cum += v;
    }
    const int b = bx>>6, ch = bx&63;
    const int base = (b*NHEADS + h)*SEQ + ch*QC + t;
    g_dt [base] = dtv;
    g_cum[base] = cum;
    if (t == 63) g_ctot[(b*NHEADS+h)*NCHUNK + ch] = cum;
  }
  __syncthreads();
  short8 a0h = *(const short8*)&Xhl[0][16*w + lane15][quad*8];
  short8 a1h = *(const short8*)&Xhl[0][16*w + lane15][quad*8 + 32];
  short8 a0l = *(const short8*)&Xhl[1][16*w + lane15][quad*8];
  short8 a1l = *(const short8*)&Xhl[1][16*w + lane15][quad*8 + 32];
  __syncthreads();   // all fragments in regs; Xhl now free for staging
  float (*stg)[68] = (float(*)[68])((float*)&Xhl[0][0][0] + (size_t)w*16*68);  // per-wave 16x68
#pragma unroll 1
  for (int g5=0; g5<5; g5++){               // 5 groups x 4 col-tiles = tiles 0..19 (n<320)
    f32x4 acc4[4];
#pragma unroll
    for (int tt=0; tt<4; tt++){
      int t = g5*4 + tt;
      const unsigned short* bph = &WinTh[(16*t + lane15)*64 + quad*8];
      const unsigned short* bpl = &WinTl[(16*t + lane15)*64 + quad*8];
      short8 b0h = *(const short8*)bph;
      short8 b1h = *(const short8*)(bph + 32);
      short8 b0l = *(const short8*)bpl;
      short8 b1l = *(const short8*)(bpl + 32);
      f32x4 acc = {0.f,0.f,0.f,0.f};
      acc = __builtin_amdgcn_mfma_f32_16x16x32_bf16(a0h, b0h, acc, 0, 0, 0);
      acc = __builtin_amdgcn_mfma_f32_16x16x32_bf16(a1h, b1h, acc, 0, 0, 0);
      acc = __builtin_amdgcn_mfma_f32_16x16x32_bf16(a0l, b0h, acc, 0, 0, 0);
      acc = __builtin_amdgcn_mfma_f32_16x16x32_bf16(a1l, b1h, acc, 0, 0, 0);
      acc = __builtin_amdgcn_mfma_f32_16x16x32_bf16(a0h, b0l, acc, 0, 0, 0);
      acc = __builtin_amdgcn_mfma_f32_16x16x32_bf16(a1h, b1l, acc, 0, 0, 0);
      acc4[tt] = acc;
    }
#pragma unroll
    for (int tt=0; tt<4; tt++)
#pragma unroll
      for (int r=0;r<4;r++)
        stg[quad*4+r][tt*16+lane15] = acc4[tt][r];
#pragma unroll
    for (int it=0; it<4; it++){
      int e = it*64 + l;
      int lr = e>>4, c4 = (e&15)<<2;
      float4 v = *(const float4*)&stg[lr][c4];
      size_t grow = row0 + 16*w + lr;
      int gcol = g5*64 + c4;
      if (g5 < 2) *(float4*)&g_z  [grow*DINNER  + gcol]          = v;
      else        *(float4*)&g_xbc[grow*CONVDIM + gcol - DINNER] = v;
    }
  }
}

// ---- K4 (MFMA): per-(b,h,chunk): register-window conv+silu, then G, Y(+exact D*x), S ----
// LDS = exactly 40 KB -> 4 blocks/CU: Gsh aliases Bsh+Csh (dead after G-MFMA reads);
// cuml/dtl live in Xf cols 64/65; ewl lives in Bt cols 64..71 (as floats).
__global__ __launch_bounds__(256,4) void k_chunkA(const float* __restrict__ conv_w,
                                                  const float* __restrict__ conv_b,
                                                  const float* __restrict__ Dp) {
  __shared__ float Xf[64][66];             // [cc][t]; cols 64=cuml(t), 65=dtl(t). 16.9 KB
  __shared__ unsigned short Xt [64][72];   // X^T (bf16), 9.2 KB
  __shared__ unsigned short Bt [32][72];   // (ew*B)^T; cols 64..71 hold ewl floats. 4.6 KB
  union BCG {
    struct { unsigned short Bsh[64][40]; unsigned short Csh[64][40]; } bc;  // 10.2 KB
    unsigned short Gsh[64][72];                                             // 9.2 KB
  };
  __shared__ BCG u;
  const int bx = blockIdx.x; const int b = bx>>7, h=(bx>>6)&1, ch=bx&63;
  const int tid = threadIdx.x;
  const size_t row0 = (size_t)b*SEQ + (size_t)ch*QC;
  const int cbase = (b*NHEADS+h)*SEQ + ch*QC;
  const float dph = Dp[h];
  if (tid < QC){
    float cl = g_cum[cbase+63];
    float cu = g_cum[cbase+tid], dtv = g_dt[cbase+tid];
    Xf[tid][64] = cu;
    Xf[tid][65] = dtv;
    ((float*)&Bt[tid>>1][64])[tid&1] = expf(cl - cu) * dtv;   // ewl[tid]
  }
  const int cc = tid & 127, half = tid >> 7, t0 = half*32;
  const int gch = (cc < 64) ? (h*64 + cc) : (64 + cc);
  const float w0 = conv_w[gch*4+0], w1 = conv_w[gch*4+1], w2 = conv_w[gch*4+2], w3 = conv_w[gch*4+3];
  const float bb = conv_b[gch];
  float v0, v1, v2;
  if (ch==0 && half==0){ v0=0.f; v1=0.f; v2=0.f; }
  else {
    v0 = g_xbc[(row0+t0-3)*CONVDIM + gch];
    v1 = g_xbc[(row0+t0-2)*CONVDIM + gch];
    v2 = g_xbc[(row0+t0-1)*CONVDIM + gch];
  }
  __syncthreads();   // cuml/dtl/ewl visible
  if (cc < 64){
#pragma unroll
    for (int blk=0; blk<4; ++blk){
      unsigned short xb[8];
#pragma unroll
      for (int j=0;j<8;j++){
        int t = t0 + blk*8 + j;
        float v3 = g_xbc[(row0+t)*CONVDIM + gch];
        float a = fmaf(w0,v0, fmaf(w1,v1, fmaf(w2,v2, fmaf(w3,v3, bb))));
        float sv = a / (1.f + expf(-a));
        Xf[cc][t] = sv;
        xb[j] = f2b(sv);
        v0=v1; v1=v2; v2=v3;
      }
      *(short8*)&Xt[cc][t0 + blk*8] = *(const short8*)xb;
    }
  } else if (cc < 96){
    const int n = cc - 64;
#pragma unroll
    for (int blk=0; blk<4; ++blk){
      unsigned short bt8[8];
#pragma unroll
      for (int j=0;j<8;j++){
        int t = t0 + blk*8 + j;
        float v3 = g_xbc[(row0+t)*CONVDIM + gch];
        float a = fmaf(w0,v0, fmaf(w1,v1, fmaf(w2,v2, fmaf(w3,v3, bb))));
        float sv = a / (1.f + expf(-a));
        u.bc.Bsh[t][n] = f2b(sv);
        float ew = ((const float*)&Bt[t>>1][64])[t&1];
        bt8[j] = f2b(sv * ew);
        v0=v1; v1=v2; v2=v3;
      }
      *(short8*)&Bt[n][t0 + blk*8] = *(const short8*)bt8;
    }
  } else {
    const int n = cc - 96;
#pragma unroll 4
    for (int t=t0; t<t0+32; t++){
      float v3 = g_xbc[(row0+t)*CONVDIM + gch];
      float a = fmaf(w0,v0, fmaf(w1,v1, fmaf(w2,v2, fmaf(w3,v3, bb))));
      float sv = a / (1.f + expf(-a));
      u.bc.Csh[t][n] = f2b(sv);
      if (h == 0) g_C[(row0+t)*DSTATE + n] = f2b(sv);
      v0=v1; v1=v2; v2=v3;
    }
  }
  __syncthreads();
  const int w = tid>>6, l = tid&63, lane15 = l&15, quad = l>>4;
  short8 afr = *(const short8*)&u.bc.Csh[16*w + lane15][quad*8];
  f32x4 gacc[4];
#pragma unroll
  for (int tn=0;tn<4;tn++){
    short8 bfr = *(const short8*)&u.bc.Bsh[16*tn + lane15][quad*8];
    f32x4 z = {0.f,0.f,0.f,0.f};
    gacc[tn] = __builtin_amdgcn_mfma_f32_16x16x32_bf16(afr, bfr, z, 0, 0, 0);
  }
  __syncthreads();   // all Bsh/Csh reads done before Gsh (aliased) is written
#pragma unroll
  for (int tn=0;tn<4;tn++){
    int s = 16*tn + lane15;
    float cs = Xf[s][64], ds = Xf[s][65];
#pragma unroll
    for (int r=0;r<4;r++){
      int t = 16*w + quad*4 + r;
      float gv = 0.f;
      if (s <= t) gv = expf(Xf[t][64]-cs) * ds * gacc[tn][r];
      u.Gsh[t][s] = f2b(gv);
    }
  }
  __syncthreads();
#pragma unroll
  for (int tn=0;tn<4;tn++){
    f32x4 acc = {0.f,0.f,0.f,0.f};
#pragma unroll
    for (int ks=0;ks<2;ks++){
      short8 a  = *(const short8*)&u.Gsh[16*w  + lane15][quad*8 + 32*ks];
      short8 bf = *(const short8*)&Xt [16*tn + lane15][quad*8 + 32*ks];
      acc = __builtin_amdgcn_mfma_f32_16x16x32_bf16(a, bf, acc, 0, 0, 0);
    }
    int p = 16*tn + lane15;
#pragma unroll
    for (int r=0;r<4;r++){
      int t = 16*w + quad*4 + r;
      g_y[(row0+t)*DINNER + h*HEADDIM + p] = acc[r] + dph * Xf[p][t];  // exact fp32 fold
    }
  }
  const size_t sb = (size_t)((b*NHEADS+h)*NCHUNK + ch) * (DSTATE*HEADDIM);
  const int tm2 = w & 1, tnb = (w>>1)*2;
#pragma unroll
  for (int tt=0;tt<2;tt++){
    int tn2 = tnb + tt;
    f32x4 acc = {0.f,0.f,0.f,0.f};
#pragma unroll
    for (int ks=0;ks<2;ks++){
      short8 a  = *(const short8*)&Bt[16*tm2 + lane15][quad*8 + 32*ks];
      short8 bf = *(const short8*)&Xt[16*tn2 + lane15][quad*8 + 32*ks];
      acc = __builtin_amdgcn_mfma_f32_16x16x32_bf16(a, bf, acc, 0, 0, 0);
    }
    int p = 16*tn2 + lane15;
#pragma unroll
    for (int r=0;r<4;r++){
      int n = 16*tm2 + quad*4 + r;
      g_S[sb + n*HEADDIM + p] = acc[r];
    }
  }
}

// ---- K5: sequential-over-chunks state scan (software-pipelined, bit-identical chain) ----
__global__ __launch_bounds__(256) void k_chunkScan() {
  __shared__ float dAc[NCHUNK];            // exp(ctot) per chunk (uniform per block)
  const int idx = blockIdx.x*256 + threadIdx.x;
  const int np = idx & 2047;
  const int bh = idx >> 11;                // uniform within a 256-thread block
  if (threadIdx.x < NCHUNK) dAc[threadIdx.x] = expf(g_ctot[bh*NCHUNK + threadIdx.x]);
  __syncthreads();
  float h = 0.f;
  const size_t base = (size_t)bh*NCHUNK*2048 + np;
#pragma unroll 1
  for (int k0=0; k0<NCHUNK; k0+=8){
    float s[8];
#pragma unroll
    for (int j=0;j<8;j++) s[j] = g_S[base + (size_t)(k0+j)*2048];   // 8 independent loads
    float hs[8];
#pragma unroll
    for (int j=0;j<8;j++){
      hs[j] = h;                                                     // state at chunk start
      h = h*dAc[k0+j] + s[j];                                        // same chain order
    }
#pragma unroll
    for (int j=0;j<8;j++) g_H[base + (size_t)(k0+j)*2048] = hs[j];
  }
}

// ---- K6 (fused): inter-chunk y + gate + RMSNorm + split-MFMA out_proj ----
// Epilogue: per-wave LDS transpose (reusing yAh) -> 4KB contiguous row stores.
__global__ __launch_bounds__(256,3) void k_fusedC(const unsigned short* __restrict__ WoutTh,
                                                  const unsigned short* __restrict__ WoutTl,
                                                  float* __restrict__ dout, int dsel) {
  __shared__ float Cl[QC][DSTATE+1];             // 8.4 KB
  __shared__ float ec[NHEADS][QC];
  __shared__ unsigned short yAh[64][136];        // 17.4 KB (reused as store staging)
  __shared__ unsigned short yAl[64][136];        // 17.4 KB
  float* __restrict__ out = (dsel==0) ? g_ping0 : (dsel==1 ? g_ping1 : dout);
  const int bx = blockIdx.x; const int b = bx>>6, ch = bx&63;
  const int tid = threadIdx.x;
  const size_t row0 = (size_t)b*SEQ + (size_t)ch*QC;
  const int w = tid>>6, l = tid&63, lane15 = l&15, quad = l>>4;
#pragma unroll
  for (int j=0;j<8;j++){ int e=tid+j*256; int s=e>>5, n=e&31;
    Cl[s][n] = b2f(g_C[(row0+s)*DSTATE + n]); }
  if (tid < 128){ int h_=tid>>6, s=tid&63;
    ec[h_][s] = expf(g_cum[(b*NHEADS+h_)*SEQ + ch*QC + s]); }
  float hr[64];
  {
    const float* H0 = &g_H[(size_t)((b*NHEADS+0)*NCHUNK + ch)*2048];
    const float* H1 = &g_H[(size_t)((b*NHEADS+1)*NCHUNK + ch)*2048];
#pragma unroll
    for (int n=0;n<32;n++){ hr[n] = H0[n*64 + l]; hr[32+n] = H1[n*64 + l]; }
  }
  __syncthreads();
#pragma unroll 1
  for (int i=0;i<16;i++){
    const int r = 16*w + i;
    const size_t row = row0 + r;
    float d0 = 0.f, d1 = 0.f;
#pragma unroll
    for (int n=0;n<32;n++){
      float c = Cl[r][n];
      d0 = fmaf(c, hr[n],    d0);
      d1 = fmaf(c, hr[32+n], d1);
    }
    float yv0 = g_y[row*DINNER + l]      + ec[0][r]*d0;
    float yv1 = g_y[row*DINNER + l + 64] + ec[1][r]*d1;
    float z0 = g_z[row*DINNER + l];
    float z1 = g_z[row*DINNER + l + 64];
    yv0 *= z0 / (1.f + expf(-z0));
    yv1 *= z1 / (1.f + expf(-z1));
    float ss = yv0*yv0 + yv1*yv1;
#pragma unroll
    for (int off=32; off>=1; off>>=1) ss += __shfl_xor(ss, off);
    float sc = rsqrtf(ss*(1.f/128.f) + 1e-5f);
    split2(yv0*sc, yAh[r][l],    yAl[r][l]);
    split2(yv1*sc, yAh[r][l+64], yAl[r][l+64]);
  }
  __syncthreads();
  short8 afh[4], afl[4];
#pragma unroll
  for (int ks=0;ks<4;ks++){
    afh[ks] = *(const short8*)&yAh[16*w + lane15][quad*8 + 32*ks];
    afl[ks] = *(const short8*)&yAl[16*w + lane15][quad*8 + 32*ks];
  }
  __syncthreads();   // all yAh reads done; reuse as per-wave staging
  float (*stgF)[68] = (float(*)[68])((float*)&yAh[0][0] + (size_t)w*16*68);
#pragma unroll
  for (int tc=0;tc<4;tc++){
    f32x4 acc = {0.f,0.f,0.f,0.f};
#pragma unroll
    for (int ks=0;ks<4;ks++){
      const unsigned short* bph = &WoutTh[(16*tc + lane15)*DINNER + quad*8 + 32*ks];
      const unsigned short* bpl = &WoutTl[(16*tc + lane15)*DINNER + quad*8 + 32*ks];
      short8 bh  = *(const short8*)bph;
      short8 blo = *(const short8*)bpl;
      acc = __builtin_amdgcn_mfma_f32_16x16x32_bf16(afh[ks], bh,  acc, 0, 0, 0);
      acc = __builtin_amdgcn_mfma_f32_16x16x32_bf16(afl[ks], bh,  acc, 0, 0, 0);
      acc = __builtin_amdgcn_mfma_f32_16x16x32_bf16(afh[ks], blo, acc, 0, 0, 0);
    }
#pragma unroll
    for (int r=0;r<4;r++)
      stgF[quad*4+r][tc*16+lane15] = acc[r];
  }
#pragma unroll
  for (int it=0; it<4; it++){
    int e = it*64 + l;
    int lr = e>>4, c4 = (e&15)<<2;
    float4 v = *(const float4*)&stgF[lr][c4];
    *(float4*)&out[(row0 + 16*w + lr)*DMODEL + c4] = v;
  }
}

extern "C" void kernel_launch(void* const* d_in, const int* in_sizes, int n_in,
                              void* d_out, int out_size, void* d_ws, size_t ws_size,
                              hipStream_t stream) {
  (void)in_sizes; (void)n_in; (void)d_ws; (void)ws_size; (void)out_size;
  const float* x       = (const float*)d_in[0];
  const float* Win     = (const float*)d_in[1];
  const float* conv_w  = (const float*)d_in[2];
  const float* conv_b  = (const float*)d_in[3];
  const float* dt_bias = (const float*)d_in[4];
  const float* A_log   = (const float*)d_in[5];
  const float* Dp      = (const float*)d_in[6];
  const float* norm_w  = (const float*)d_in[7];
  const float* Wout    = (const float*)d_in[8];

  k_prep<<<(8*(NPAD*DMODEL + DMODEL*DINNER) + 255)/256, 256, 0, stream>>>(Win, Wout, norm_w);

  unsigned short *winTh, *winTl, *woutTh, *woutTl;
  hipGetSymbolAddress((void**)&winTh,  HIP_SYMBOL(g_WinTh));
  hipGetSymbolAddress((void**)&winTl,  HIP_SYMBOL(g_WinTl));
  hipGetSymbolAddress((void**)&woutTh, HIP_SYMBOL(g_WoutTh));
  hipGetSymbolAddress((void**)&woutTl, HIP_SYMBOL(g_WoutTl));

  for (int layer = 0; layer < 8; ++layer) {
    const int insel = (layer==0) ? 0 : ((((layer-1)&1)==0) ? 1 : 2);
    const int dsel  = (layer==7) ? 2 : ((layer&1)==0 ? 0 : 1);

    k_inproj<<<BL/64, 256, 0, stream>>>(x, insel,
                                        winTh + (size_t)layer*NPAD*DMODEL,
                                        winTl + (size_t)layer*NPAD*DMODEL,
                                        Win + (size_t)layer*DMODEL*PROJ,
                                        dt_bias + layer*NHEADS, A_log + layer*NHEADS);
    k_chunkA<<<BATCH*NHEADS*NCHUNK, 256, 0, stream>>>(conv_w + (size_t)layer*CONVDIM*4,
                                                      conv_b + (size_t)layer*CONVDIM,
                                                      Dp + layer*NHEADS);
    k_chunkScan<<<(BATCH*NHEADS*DSTATE*HEADDIM)/256, 256, 0, stream>>>();
    k_fusedC<<<BATCH*NCHUNK, 256, 0, stream>>>(woutTh + (size_t)layer*DMODEL*DINNER,
                                               woutTl + (size_t)layer*DMODEL*DINNER,
                                               (float*)d_out, dsel);
  }
}